// Round 2
// baseline (22999.072 us; speedup 1.0000x reference)
//
#include <hip/hip_runtime.h>

#define NN 100000
#define NE 1600000
#define DD 128

using u16 = unsigned short;
using u32 = unsigned int;

__device__ __forceinline__ float bf2f(u16 h){ return __uint_as_float(((u32)h) << 16); }
__device__ __forceinline__ u16 f2bf(float f){
  u32 u = __float_as_uint(f);
  u += 0x7FFFu + ((u >> 16) & 1u);   // round-to-nearest-even
  return (u16)(u >> 16);
}
// integer index load: w64=1 -> int64 little-endian (read low word), else int32
__device__ __forceinline__ int ld_idx(const int* __restrict__ p, long long k, int w64){
  return w64 ? p[2*k] : p[k];
}
// float load: f32=1 -> fp32 buffer, else bf16 buffer
__device__ __forceinline__ float ldf(const void* __restrict__ p, long long k, int f32){
  return f32 ? ((const float*)p)[k] : bf2f(((const u16*)p)[k]);
}

// flags[0] = edge_index is int64 layout; flags[1] = float tensors are fp32
__global__ void detect_kernel(const int* __restrict__ ei, const u16* __restrict__ xw,
                              int* __restrict__ flags){
  if (threadIdx.x == 0 && blockIdx.x == 0){
    int all0 = 1;
    for (int k = 1; k < 256; k += 2) all0 &= (ei[k] == 0);
    flags[0] = all0;  // int64 values in [0,2^31) -> odd words all zero
    // if x is fp32, the low u16 of each 4-byte group is uniform mantissa bits;
    // if bf16, it is a bf16 of N(0,1): exponent field clustered near 127.
    int cnt = 0;
    for (int i = 0; i < 128; ++i){
      u16 w = xw[2*i];
      int e = (w >> 7) & 0xFF;
      cnt += (e >= 100 && e <= 130);
    }
    flags[1] = (cnt < 64);  // few matches -> uniform bits -> fp32
  }
}

__global__ __launch_bounds__(256) void deg_kernel(const void* __restrict__ ea, long long ea_off,
    const int* __restrict__ ei, long long col_off,
    const int* __restrict__ flags, float* __restrict__ deg){
  int e = blockIdx.x*256 + threadIdx.x;
  if (e >= NE) return;
  int col = ld_idx(ei, col_off + e, flags[0]);
  atomicAdd(deg + col, ldf(ea, ea_off + e, flags[1]));
}

__global__ __launch_bounds__(256) void dinv_kernel(float* __restrict__ deg){
  int n = blockIdx.x*256 + threadIdx.x;
  if (n >= NN) return;
  float d = deg[n];
  deg[n] = (d > 0.f) ? rsqrtf(d) : 0.f;
}

// agg[col] += dinv[row]*w*dinv[col] * h[row]; 16 threads/edge, 8 dims each
__global__ __launch_bounds__(256) void scatter_kernel(
    const void* __restrict__ hbase, long long h_off,
    const void* __restrict__ ea, long long ea_off,
    const int* __restrict__ ei, long long row_off, long long col_off,
    const float* __restrict__ dinv, const int* __restrict__ flags,
    float* __restrict__ agg){
  long long tid = (long long)blockIdx.x*256 + threadIdx.x;
  long long e = tid >> 4;
  int part = (int)(tid & 15);
  if (e >= NE) return;
  int w64 = flags[0], f32 = flags[1];
  int row = ld_idx(ei, row_off + e, w64);
  int col = ld_idx(ei, col_off + e, w64);
  float w = ldf(ea, ea_off + e, f32);
  float c = dinv[row] * w * dinv[col];
  if (c == 0.f) return;
  float v[8];
  if (f32){
    const float4* p = (const float4*)((const float*)hbase + h_off + (long long)row*DD) + part*2;
    float4 a = p[0], b = p[1];
    v[0]=a.x; v[1]=a.y; v[2]=a.z; v[3]=a.w; v[4]=b.x; v[5]=b.y; v[6]=b.z; v[7]=b.w;
  } else {
    const uint4* p = (const uint4*)((const u16*)hbase + h_off + (long long)row*DD) + part;
    uint4 a = p[0];
    v[0]=bf2f((u16)(a.x & 0xFFFF)); v[1]=bf2f((u16)(a.x >> 16));
    v[2]=bf2f((u16)(a.y & 0xFFFF)); v[3]=bf2f((u16)(a.y >> 16));
    v[4]=bf2f((u16)(a.z & 0xFFFF)); v[5]=bf2f((u16)(a.z >> 16));
    v[6]=bf2f((u16)(a.w & 0xFFFF)); v[7]=bf2f((u16)(a.w >> 16));
  }
  float* dst = agg + (long long)col*DD + part*8;
  #pragma unroll
  for (int j = 0; j < 8; ++j) atomicAdd(dst + j, c*v[j]);
}

// out = relu(in @ W^T + bias); 32 nodes/block, thread tile 4 nodes x 4 dims.
// W staged in LDS as bf16 (stride 132 -> 2-way banks, free); fp32 accumulate.
__global__ __launch_bounds__(256) void gemm_kernel(
    const void* __restrict__ in, int in_force_f32,
    const void* __restrict__ W, long long w_off,
    const void* __restrict__ bias, long long b_off,
    const int* __restrict__ flags,
    void* __restrict__ outb, long long out_off){
  __shared__ u16  wsm[DD][DD+4];   // 33792 B
  __shared__ float xsm[32][DD+4];  // 16896 B -> 50688 B total
  int t = threadIdx.x;
  int f32 = flags[1];
  int inf32 = in_force_f32 | f32;

  for (int i = t; i < DD*DD; i += 256){
    u16 wv = f32 ? f2bf(((const float*)W)[w_off + i]) : ((const u16*)W)[w_off + i];
    wsm[i >> 7][i & 127] = wv;
  }
  long long rowbase = (long long)blockIdx.x * 32;
  for (int i = t; i < 32*DD; i += 256){
    int n = i >> 7, k = i & 127;
    long long gi = (rowbase + n)*DD + k;
    xsm[n][k] = inf32 ? ((const float*)in)[gi] : bf2f(((const u16*)in)[gi]);
  }
  __syncthreads();

  int d0 = t & 31;
  int n0 = (t >> 5) * 4;
  float acc[4][4] = {};
  #pragma unroll 4
  for (int k = 0; k < DD; k += 2){
    float2 xv[4];
    #pragma unroll
    for (int a = 0; a < 4; ++a) xv[a] = *(const float2*)&xsm[n0+a][k];
    #pragma unroll
    for (int j = 0; j < 4; ++j){
      u32 wv = *(const u32*)&wsm[d0 + 32*j][k];
      float w0 = bf2f((u16)(wv & 0xFFFF));
      float w1 = bf2f((u16)(wv >> 16));
      #pragma unroll
      for (int a = 0; a < 4; ++a){
        acc[a][j] += xv[a].x * w0;
        acc[a][j] += xv[a].y * w1;
      }
    }
  }
  #pragma unroll
  for (int a = 0; a < 4; ++a){
    long long gn = rowbase + n0 + a;
    #pragma unroll
    for (int j = 0; j < 4; ++j){
      int d = d0 + 32*j;
      float v = acc[a][j] + ldf(bias, b_off + d, f32);
      v = fmaxf(v, 0.f);
      long long gi = out_off + gn*DD + d;
      if (f32) ((float*)outb)[gi] = v;
      else     ((u16*)outb)[gi] = f2bf(v);
    }
  }
}

extern "C" void kernel_launch(void* const* d_in, const int* in_sizes, int n_in,
                              void* d_out, int out_size, void* d_ws, size_t ws_size,
                              hipStream_t stream){
  const void* x      = d_in[0];
  const int*  ei     = (const int*)d_in[1];
  const void* ea     = d_in[2];
  const void* lin_w  = d_in[3];
  const void* lin_b  = d_in[4];
  const void* conv_w = d_in[5];
  const void* conv_b = d_in[6];
  void* out = d_out;

  char* ws = (char*)d_ws;
  int*   flags = (int*)ws;                      // 256 B
  float* deg   = (float*)(ws + 256);            // 400 KB
  float* agg   = (float*)(ws + 256 + (size_t)NN*4);  // 51.2 MB -> total ~51.6 MB

  detect_kernel<<<1, 64, 0, stream>>>(ei, (const u16*)x, flags);

  // layer 0: out[0] = relu(x @ lin_w.T + lin_b)
  gemm_kernel<<<(NN+31)/32, 256, 0, stream>>>(x, 0, lin_w, 0, lin_b, 0, flags, out, 0);

  for (int i = 0; i < 4; ++i){
    long long h_off = (long long)i*NN*DD;
    long long o_off = (long long)(i+1)*NN*DD;
    long long row_off = ((long long)i*2 + 0)*NE;
    long long col_off = ((long long)i*2 + 1)*NE;
    long long ea_off  = (long long)i*NE;

    hipMemsetAsync(deg, 0, (size_t)NN*4, stream);
    deg_kernel<<<(NE+255)/256, 256, 0, stream>>>(ea, ea_off, ei, col_off, flags, deg);
    dinv_kernel<<<(NN+255)/256, 256, 0, stream>>>(deg);

    hipMemsetAsync(agg, 0, (size_t)NN*DD*4, stream);
    scatter_kernel<<<(int)(((long long)NE*16 + 255)/256), 256, 0, stream>>>(
        out, h_off, ea, ea_off, ei, row_off, col_off, deg, flags, agg);

    // out[i+1] = relu(agg @ conv_w[i].T + conv_b[i])
    gemm_kernel<<<(NN+31)/32, 256, 0, stream>>>(agg, 1, conv_w, (long long)i*DD*DD,
                                                conv_b, (long long)i*DD, flags, out, o_off);
  }
}

// Round 3
// 2671.624 us; speedup vs baseline: 8.6086x; 8.6086x over previous
//
#include <hip/hip_runtime.h>

#define NN 100000
#define NE 1600000
#define DD 128
#define SCAN_CHUNK 1024
#define NBLK ((NN + SCAN_CHUNK - 1) / SCAN_CHUNK)   // 98

using u16 = unsigned short;
using u32 = unsigned int;

__device__ __forceinline__ float bf2f(u16 h){ return __uint_as_float(((u32)h) << 16); }
__device__ __forceinline__ u16 f2bf(float f){
  u32 u = __float_as_uint(f);
  u += 0x7FFFu + ((u >> 16) & 1u);   // round-to-nearest-even
  return (u16)(u >> 16);
}
__device__ __forceinline__ int ld_idx(const int* __restrict__ p, long long k, int w64){
  return w64 ? p[2*k] : p[k];
}
__device__ __forceinline__ float ldf(const void* __restrict__ p, long long k, int f32){
  return f32 ? ((const float*)p)[k] : bf2f(((const u16*)p)[k]);
}

// flags[0] = edge_index is int64 layout; flags[1] = float tensors are fp32
__global__ void detect_kernel(const int* __restrict__ ei, const u16* __restrict__ xw,
                              int* __restrict__ flags){
  if (threadIdx.x == 0 && blockIdx.x == 0){
    int all0 = 1;
    for (int k = 1; k < 256; k += 2) all0 &= (ei[k] == 0);
    flags[0] = all0;
    int cnt = 0;
    for (int i = 0; i < 128; ++i){
      u16 w = xw[2*i];
      int e = (w >> 7) & 0xFF;
      cnt += (e >= 100 && e <= 130);
    }
    flags[1] = (cnt < 64);
  }
}

// deg[col] += w ; cnt[col] += 1
__global__ __launch_bounds__(256) void hist_kernel(const void* __restrict__ ea, long long ea_off,
    const int* __restrict__ ei, long long col_off,
    const int* __restrict__ flags, float* __restrict__ deg, int* __restrict__ cnt){
  int e = blockIdx.x*256 + threadIdx.x;
  if (e >= NE) return;
  int col = ld_idx(ei, col_off + e, flags[0]);
  atomicAdd(deg + col, ldf(ea, ea_off + e, flags[1]));
  atomicAdd(cnt + col, 1);
}

__global__ __launch_bounds__(256) void dinv_kernel(float* __restrict__ deg){
  int n = blockIdx.x*256 + threadIdx.x;
  if (n >= NN) return;
  float d = deg[n];
  deg[n] = (d > 0.f) ? rsqrtf(d) : 0.f;
}

// ---- exclusive scan of cnt[NN] into base[NN]  (3 kernels) ----
__global__ __launch_bounds__(256) void scan_block_kernel(const int* __restrict__ cnt,
    int* __restrict__ base, int* __restrict__ bsums){
  __shared__ int sm[256];
  int b = blockIdx.x, t = threadIdx.x;
  int i0 = b*SCAN_CHUNK + t*4;
  int v[4];
  #pragma unroll
  for (int j = 0; j < 4; ++j) v[j] = (i0 + j < NN) ? cnt[i0 + j] : 0;
  int s = v[0] + v[1] + v[2] + v[3];
  sm[t] = s;
  __syncthreads();
  for (int off = 1; off < 256; off <<= 1){
    int add = (t >= off) ? sm[t - off] : 0;
    __syncthreads();
    sm[t] += add;
    __syncthreads();
  }
  int run = sm[t] - s;          // exclusive prefix of this thread
  if (t == 255) bsums[b] = sm[255];
  #pragma unroll
  for (int j = 0; j < 4; ++j){
    if (i0 + j < NN) base[i0 + j] = run;
    run += v[j];
  }
}

__global__ void scan_sums_kernel(int* __restrict__ bsums, int nb){
  __shared__ int sm[256];
  int t = threadIdx.x;
  int v = (t < nb) ? bsums[t] : 0;
  sm[t] = v;
  __syncthreads();
  for (int off = 1; off < 256; off <<= 1){
    int add = (t >= off) ? sm[t - off] : 0;
    __syncthreads();
    sm[t] += add;
    __syncthreads();
  }
  if (t < nb) bsums[t] = sm[t] - v;   // exclusive
}

__global__ __launch_bounds__(256) void scan_add_kernel(int* __restrict__ base,
    const int* __restrict__ bsums, int* __restrict__ cursor){
  int i = blockIdx.x*256 + threadIdx.x;
  if (i >= NN) return;
  int b = base[i] + bsums[i / SCAN_CHUNK];
  base[i] = b;
  cursor[i] = b;
}

// rows[pos]=row, coef[pos]=dinv[row]*w*dinv[col] at pos=cursor[col]++
__global__ __launch_bounds__(256) void fill_kernel(const void* __restrict__ ea, long long ea_off,
    const int* __restrict__ ei, long long row_off, long long col_off,
    const float* __restrict__ dinv, const int* __restrict__ flags,
    int* __restrict__ cursor, int* __restrict__ rows, float* __restrict__ coef){
  int e = blockIdx.x*256 + threadIdx.x;
  if (e >= NE) return;
  int w64 = flags[0];
  int row = ld_idx(ei, row_off + e, w64);
  int col = ld_idx(ei, col_off + e, w64);
  float w = ldf(ea, ea_off + e, flags[1]);
  int pos = atomicAdd(cursor + col, 1);
  rows[pos] = row;
  coef[pos] = dinv[row] * w * dinv[col];
}

// one wave per node: agg[n] = sum_j coef[j] * h[rows[j]]
__global__ __launch_bounds__(256) void aggregate_kernel(
    const void* __restrict__ hbase, long long h_off,
    const int* __restrict__ rows, const float* __restrict__ coef,
    const int* __restrict__ base, const int* __restrict__ cnt,
    const int* __restrict__ flags, void* __restrict__ agg, int agg_f32){
  int wid = (int)(((long long)blockIdx.x*256 + threadIdx.x) >> 6);
  int l = threadIdx.x & 63;
  if (wid >= NN) return;
  int f32 = flags[1];
  int s = base[wid], e = s + cnt[wid];
  float ax = 0.f, ay = 0.f;
  if (f32){
    const float2* hp = (const float2*)((const float*)hbase + h_off);
    for (int j = s; j < e; ++j){
      int r = rows[j];
      float c = coef[j];
      float2 hv = hp[(long long)r*64 + l];
      ax += c*hv.x; ay += c*hv.y;
    }
  } else {
    const u32* hp = (const u32*)((const u16*)hbase + h_off);
    for (int j = s; j < e; ++j){
      int r = rows[j];
      float c = coef[j];
      u32 hv = hp[(long long)r*64 + l];
      ax += c*bf2f((u16)(hv & 0xFFFF));
      ay += c*bf2f((u16)(hv >> 16));
    }
  }
  if (agg_f32) ((float2*)agg)[(long long)wid*64 + l] = make_float2(ax, ay);
  else         ((u32*)agg)[(long long)wid*64 + l] = ((u32)f2bf(ay) << 16) | (u32)f2bf(ax);
}

// out = relu(in @ W^T + bias); in_mode: 0=bf16, 1=f32, 2=follow flags[1]
__global__ __launch_bounds__(256) void gemm_kernel(
    const void* __restrict__ in, int in_mode,
    const void* __restrict__ W, long long w_off,
    const void* __restrict__ bias, long long b_off,
    const int* __restrict__ flags,
    void* __restrict__ outb, long long out_off){
  __shared__ u16  wsm[DD][DD+4];
  __shared__ float xsm[32][DD+4];
  int t = threadIdx.x;
  int f32 = flags[1];
  int inf32 = (in_mode == 2) ? f32 : in_mode;

  for (int i = t; i < DD*DD; i += 256){
    u16 wv = f32 ? f2bf(((const float*)W)[w_off + i]) : ((const u16*)W)[w_off + i];
    wsm[i >> 7][i & 127] = wv;
  }
  long long rowbase = (long long)blockIdx.x * 32;
  for (int i = t; i < 32*DD; i += 256){
    int n = i >> 7, k = i & 127;
    long long gi = (rowbase + n)*DD + k;
    xsm[n][k] = inf32 ? ((const float*)in)[gi] : bf2f(((const u16*)in)[gi]);
  }
  __syncthreads();

  int d0 = t & 31;
  int n0 = (t >> 5) * 4;
  float acc[4][4] = {};
  #pragma unroll 4
  for (int k = 0; k < DD; k += 2){
    float2 xv[4];
    #pragma unroll
    for (int a = 0; a < 4; ++a) xv[a] = *(const float2*)&xsm[n0+a][k];
    #pragma unroll
    for (int j = 0; j < 4; ++j){
      u32 wv = *(const u32*)&wsm[d0 + 32*j][k];
      float w0 = bf2f((u16)(wv & 0xFFFF));
      float w1 = bf2f((u16)(wv >> 16));
      #pragma unroll
      for (int a = 0; a < 4; ++a){
        acc[a][j] += xv[a].x * w0;
        acc[a][j] += xv[a].y * w1;
      }
    }
  }
  #pragma unroll
  for (int a = 0; a < 4; ++a){
    long long gn = rowbase + n0 + a;
    #pragma unroll
    for (int j = 0; j < 4; ++j){
      int d = d0 + 32*j;
      float v = acc[a][j] + ldf(bias, b_off + d, f32);
      v = fmaxf(v, 0.f);
      long long gi = out_off + gn*DD + d;
      if (f32) ((float*)outb)[gi] = v;
      else     ((u16*)outb)[gi] = f2bf(v);
    }
  }
}

extern "C" void kernel_launch(void* const* d_in, const int* in_sizes, int n_in,
                              void* d_out, int out_size, void* d_ws, size_t ws_size,
                              hipStream_t stream){
  const void* x      = d_in[0];
  const int*  ei     = (const int*)d_in[1];
  const void* ea     = d_in[2];
  const void* lin_w  = d_in[3];
  const void* lin_b  = d_in[4];
  const void* conv_w = d_in[5];
  const void* conv_b = d_in[6];
  void* out = d_out;

  char* ws = (char*)d_ws;
  size_t o = 0;
  auto alloc = [&](size_t bytes){ void* p = ws + o; o = (o + bytes + 255) & ~(size_t)255; return p; };
  int*   flags  = (int*)  alloc(256);
  float* deg    = (float*)alloc((size_t)NN*4);   // deg then dinv in-place
  int*   cnt    = (int*)  alloc((size_t)NN*4);
  int*   base   = (int*)  alloc((size_t)NN*4);
  int*   cursor = (int*)  alloc((size_t)NN*4);
  int*   bsums  = (int*)  alloc(4096);
  int*   rows   = (int*)  alloc((size_t)NE*4);
  float* coef   = (float*)alloc((size_t)NE*4);
  size_t fixed = o;
  int agg_f32 = (ws_size >= fixed + (size_t)NN*DD*4) ? 1 : 0;
  void* agg = alloc((size_t)NN*DD*(agg_f32 ? 4 : 2));

  detect_kernel<<<1, 64, 0, stream>>>(ei, (const u16*)x, flags);

  // layer 0: out[0] = relu(x @ lin_w.T + lin_b)
  gemm_kernel<<<(NN+31)/32, 256, 0, stream>>>(x, 2, lin_w, 0, lin_b, 0, flags, out, 0);

  for (int i = 0; i < 4; ++i){
    long long h_off   = (long long)i*NN*DD;
    long long o_off   = (long long)(i+1)*NN*DD;
    long long row_off = ((long long)i*2 + 0)*NE;
    long long col_off = ((long long)i*2 + 1)*NE;
    long long ea_off  = (long long)i*NE;

    hipMemsetAsync(deg, 0, (size_t)NN*4, stream);
    hipMemsetAsync(cnt, 0, (size_t)NN*4, stream);
    hist_kernel<<<(NE+255)/256, 256, 0, stream>>>(ea, ea_off, ei, col_off, flags, deg, cnt);
    dinv_kernel<<<(NN+255)/256, 256, 0, stream>>>(deg);

    scan_block_kernel<<<NBLK, 256, 0, stream>>>(cnt, base, bsums);
    scan_sums_kernel<<<1, 256, 0, stream>>>(bsums, NBLK);
    scan_add_kernel<<<(NN+255)/256, 256, 0, stream>>>(base, bsums, cursor);

    fill_kernel<<<(NE+255)/256, 256, 0, stream>>>(ea, ea_off, ei, row_off, col_off,
                                                  deg, flags, cursor, rows, coef);

    aggregate_kernel<<<(NN*64 + 255)/256, 256, 0, stream>>>(out, h_off, rows, coef,
                                                            base, cnt, flags, agg, agg_f32);

    gemm_kernel<<<(NN+31)/32, 256, 0, stream>>>(agg, agg_f32 ? 1 : 0,
                                                conv_w, (long long)i*DD*DD,
                                                conv_b, (long long)i*DD, flags, out, o_off);
  }
}